// Round 4
// baseline (228.003 us; speedup 1.0000x reference)
//
#include <hip/hip_runtime.h>

// x: [8, 1, 160, 160, 160] fp32; log_sigma: [3] fp32; out: scalar fp32.
// loss = -(mean_d(k) + mean_h(k) + mean_w(k)) / 3, k = exp(-sq/(2*sigma^2)),
// sq[b][pair] = sum over remaining dims of adjacent-slice squared diff.
//
// R4 design: FULL UNROLL, all accumulators in registers (d-axis keyed by the
// compile-time iteration index -> aD[10]); no in-loop LDS/atomic/shuffle/
// barrier/register-rolling. R1-R3 all ran at ~77us regardless of structure:
// isolated L3-warm replay still took 76us => every load was serialized at
// ~450cyc latency (loop-carried reg copies + per-iter shfl chain forced
// near-vmcnt(0) drains each iteration). Unrolling makes copies SSA renames
// and lets the compiler hoist loads across slices.

constexpr int Wd = 160;
constexpr int SLICE = 160 * 160;          // floats per (b,d) slice
constexpr long BSTRIDE = 160L * 25600;    // floats per batch
constexpr int NB = 8;
constexpr int NPAIR = 159;                // slice pairs per axis
constexpr int WS_FLOATS = 3 * NB * NPAIR; // 3816

__global__ void zero_ws_kernel(float* __restrict__ ws) {
    int i = blockIdx.x * 256 + threadIdx.x;
    if (i < WS_FLOATS) ws[i] = 0.f;
}

__device__ __forceinline__ float sq4(const float4& a, const float4& c) {
    float e0 = a.x - c.x, e1 = a.y - c.y, e2 = a.z - c.z, e3 = a.w - c.w;
    return e0 * e0 + e1 * e1 + e2 * e2 + e3 * e3;
}

// Grid: 8 b * 10 h-chunks * 16 d-segments = 1280 blocks, 320 threads.
// Thread t: float4 col fw=t%40, ADJACENT rows r1=h0+2*(t/40), r2=r1+1.
// Per slice: v1,v2 (owned rows), hv (row r2+1 reload, for pair keyed r2),
// s1,s2 (w-boundary scalars). Pair (r1,r2) is register-local (key r1).
__global__ __launch_bounds__(320) void diff3_kernel(const float* __restrict__ x,
                                                    float* __restrict__ ws) {
    __shared__ float accD[10];
    __shared__ float accH[16];
    __shared__ float accW[160];

    const int t = threadIdx.x;
    const int bid = blockIdx.x;
    const int b = bid / 160;
    const int rem = bid % 160;
    const int s = rem / 10;    // d-segment 0..15
    const int hc = rem % 10;   // h-chunk 0..9
    const int h0 = hc * 16;
    const int d0 = s * 10;
    const bool lastSeg = (s == 15);

    const int fw = t % 40;
    const int rp = t / 40;                    // 0..7
    const int r1 = h0 + 2 * rp;               // even row
    // r2 = r1+1 (odd row). Pair (r2, r2+1) exists unless r2==159.
    const bool hOK = !(hc == 9 && rp == 7);
    const bool sOK = (fw < 39);

    if (t < 10)              accD[t] = 0.f;
    if (t >= 32 && t < 48)   accH[t - 32] = 0.f;
    if (t >= 64 && t < 224)  accW[t - 64] = 0.f;

    const float* rowA = x + (size_t)b * BSTRIDE + (size_t)d0 * SLICE
                          + (size_t)r1 * Wd + (size_t)fw * 4;

    float aW0 = 0.f, aW1 = 0.f, aW2 = 0.f, aW3 = 0.f;
    float aH1 = 0.f, aH2 = 0.f;
    float aD[10];
#pragma unroll
    for (int j = 0; j < 10; ++j) aD[j] = 0.f;

    float4 pv1, pv2;

#pragma unroll
    for (int it = 0; it < 10; ++it) {
        const float* sp = rowA + (size_t)it * SLICE;
        const float4 v1 = *(const float4*)sp;
        const float4 v2 = *(const float4*)(sp + Wd);
        float4 hv;
        if (hOK) hv = *(const float4*)(sp + 2 * Wd);
        float s1 = 0.f, s2 = 0.f;
        if (sOK) { s1 = sp[4]; s2 = sp[Wd + 4]; }

        // w-axis: 3 internal pairs per row + boundary via scalar
        float dw;
        dw = v1.y - v1.x; aW0 += dw * dw;
        dw = v1.z - v1.y; aW1 += dw * dw;
        dw = v1.w - v1.z; aW2 += dw * dw;
        dw = v2.y - v2.x; aW0 += dw * dw;
        dw = v2.z - v2.y; aW1 += dw * dw;
        dw = v2.w - v2.z; aW2 += dw * dw;
        if (sOK) {
            dw = s1 - v1.w; aW3 += dw * dw;
            dw = s2 - v2.w; aW3 += dw * dw;
        }
        // h-axis: local pair (r1,r2) key r1; reload pair (r2,r2+1) key r2
        aH1 += sq4(v2, v1);
        if (hOK) aH2 += sq4(hv, v2);
        // d-axis: pair d0+it-1, register-keyed by compile-time index
        if (it > 0) aD[it - 1] += sq4(v1, pv1) + sq4(v2, pv2);
        pv1 = v1; pv2 = v2;  // SSA renames under full unroll
    }
    // d-halo pair d0+9 (slice d0+10 vs d0+9)
    if (!lastSeg) {
        const float* sp = rowA + (size_t)10 * SLICE;
        const float4 v1 = *(const float4*)sp;
        const float4 v2 = *(const float4*)(sp + Wd);
        aD[9] += sq4(v1, pv1) + sq4(v2, pv2);
    }

    __syncthreads();  // accD/accH/accW zeroed before atomics

    // flush register accumulators -> LDS
    atomicAdd(&accH[r1 - h0], aH1);
    if (hOK) atomicAdd(&accH[r1 - h0 + 1], aH2);
    atomicAdd(&accW[fw * 4 + 0], aW0);
    atomicAdd(&accW[fw * 4 + 1], aW1);
    atomicAdd(&accW[fw * 4 + 2], aW2);
    if (sOK) atomicAdd(&accW[fw * 4 + 3], aW3);
#pragma unroll
    for (int j = 0; j < 10; ++j) {
        float dd = aD[j];
        for (int off = 32; off > 0; off >>= 1) dd += __shfl_down(dd, off, 64);
        if ((t & 63) == 0) atomicAdd(&accD[j], dd);
    }
    __syncthreads();

    // flush block accumulators -> global workspace
    float* wsD = ws;
    float* wsH = ws + NB * NPAIR;
    float* wsW = ws + 2 * NB * NPAIR;
    const int nd = lastSeg ? 9 : 10;
    if (t < nd) atomicAdd(&wsD[b * NPAIR + d0 + t], accD[t]);
    if (t >= 32 && t < 48) {
        int r = t - 32;
        if (h0 + r < 159) atomicAdd(&wsH[b * NPAIR + h0 + r], accH[r]);
    }
    if (t >= 64 && t < 64 + 159) {
        int k = t - 64;
        atomicAdd(&wsW[b * NPAIR + k], accW[k]);
    }
}

__global__ __launch_bounds__(256) void finalize_kernel(const float* __restrict__ ws,
                                                       const float* __restrict__ log_sigma,
                                                       float* __restrict__ out) {
    __shared__ float ssum;
    const int t = threadIdx.x;
    if (t == 0) ssum = 0.f;
    __syncthreads();

    const float f0 = -0.5f * expf(-2.f * log_sigma[0]);  // -1/(2*sigma_d^2)
    const float f1 = -0.5f * expf(-2.f * log_sigma[1]);
    const float f2 = -0.5f * expf(-2.f * log_sigma[2]);

    float acc = 0.f;
    const int n = NB * NPAIR;  // 1272 per axis
    for (int i = t; i < n; i += 256) acc += expf(ws[i] * f0);
    for (int i = t; i < n; i += 256) acc += expf(ws[n + i] * f1);
    for (int i = t; i < n; i += 256) acc += expf(ws[2 * n + i] * f2);

    for (int off = 32; off > 0; off >>= 1) acc += __shfl_down(acc, off, 64);
    if ((t & 63) == 0) atomicAdd(&ssum, acc);
    __syncthreads();
    if (t == 0) out[0] = -ssum / (float)(3 * NB * NPAIR);
}

extern "C" void kernel_launch(void* const* d_in, const int* in_sizes, int n_in,
                              void* d_out, int out_size, void* d_ws, size_t ws_size,
                              hipStream_t stream) {
    const float* x = (const float*)d_in[0];
    const float* log_sigma = (const float*)d_in[1];
    float* out = (float*)d_out;
    float* ws = (float*)d_ws;

    zero_ws_kernel<<<(WS_FLOATS + 255) / 256, 256, 0, stream>>>(ws);
    diff3_kernel<<<8 * 10 * 16, 320, 0, stream>>>(x, ws);
    finalize_kernel<<<1, 256, 0, stream>>>(ws, log_sigma, out);
}